// Round 4
// baseline (163.232 us; speedup 1.0000x reference)
//
#include <hip/hip_runtime.h>

#define GRID_S 7
#define NUM_CLASSES 80
#define D_DIM 90
#define LAMBDA_COORD 5.0f
#define LAMBDA_NOOBJ 0.5f
#define EPS_IOU 1e-6f
#define EPS_SQRT 1e-6f

// Stream blocks: GA*256 threads must be a multiple of 45 (45 float4 == 2 cells,
// so each thread's phase within the 2-cell group is loop-invariant).
// 630*256 = 161280 = 45*3584.
#define GA 630

__device__ __forceinline__ float iou_img(float cx1, float cy1, float w1, float h1,
                                         float cx2, float cy2, float w2, float h2) {
    float ixmin = fmaxf(cx1 - w1 * 0.5f, cx2 - w2 * 0.5f);
    float iymin = fmaxf(cy1 - h1 * 0.5f, cy2 - h2 * 0.5f);
    float ixmax = fminf(cx1 + w1 * 0.5f, cx2 + w2 * 0.5f);
    float iymax = fminf(cy1 + h1 * 0.5f, cy2 + h2 * 0.5f);
    float iw = fmaxf(ixmax - ixmin, 0.0f);
    float ih = fmaxf(iymax - iymin, 0.0f);
    float inter = iw * ih;
    float uni = w1 * h1 + w2 * h2 - inter;
    return inter / (uni + EPS_IOU);
}

// part layout: per block, 4 floats: [n_obj, coord, conf, cls]
__global__ __launch_bounds__(256) void yolo_main_kernel(
        const float* __restrict__ pred, const float* __restrict__ targ,
        float* __restrict__ part, int ncells) {
    const int tid = threadIdx.x;
    float v_obj = 0.0f, v_coord = 0.0f, v_conf = 0.0f, v_cls = 0.0f;

    if (blockIdx.x < GA) {
        // ================= stream path: class loss =================
        const int NF4 = (ncells * D_DIM) >> 2;     // 90*ncells/4 (ncells even)
        const int T = GA * 256;                    // 161280, multiple of 45
        const int t = blockIdx.x * 256 + tid;
        const int phase = t % 45;                  // float4 position within 2-cell group
        int g = t / 45;                            // 2-cell group index
        const int GSTRIDE = T / 45;                // 3584

        // per-element loop-invariant weights:
        // element e is float index phase*4+e in [0,180): cell offset ce, d-index de.
        // w0[e]/w1[e] = 1 iff (de>=10) and the element belongs to cell g*2+0 / g*2+1.
        float w0[4], w1[4];
        #pragma unroll
        for (int e = 0; e < 4; ++e) {
            int fe = phase * 4 + e;
            int ce = (fe >= 90) ? 1 : 0;
            int de = fe - 90 * ce;
            float cw = (de >= 10) ? 1.0f : 0.0f;
            w0[e] = ce ? 0.0f : cw;
            w1[e] = ce ? cw : 0.0f;
        }

        const float4* p4 = (const float4*)pred;
        const float4* t4 = (const float4*)targ;
        float acc = 0.0f;
        for (int j = t; j < NF4; j += T, g += GSTRIDE) {
            float4 p = p4[j];
            float4 tv = t4[j];
            const float* ob = targ + (size_t)g * 180;
            float o0 = ob[4];
            float o1 = ob[94];
            float f0 = (o0 == 1.0f) ? 1.0f : 0.0f;
            float f1 = (o1 == 1.0f) ? 1.0f : 0.0f;
            float d0 = p.x - tv.x;
            float d1 = p.y - tv.y;
            float d2 = p.z - tv.z;
            float d3 = p.w - tv.w;
            acc = fmaf(d0 * d0, fmaf(w1[0], f1, w0[0] * f0), acc);
            acc = fmaf(d1 * d1, fmaf(w1[1], f1, w0[1] * f0), acc);
            acc = fmaf(d2 * d2, fmaf(w1[2], f1, w0[2] * f0), acc);
            acc = fmaf(d3 * d3, fmaf(w1[3], f1, w0[3] * f0), acc);
        }
        v_cls = acc * (1.0f / (float)NUM_CLASSES);
    } else {
        // ================= gather path: box / conf / n_obj =================
        const int cell = (blockIdx.x - GA) * 256 + tid;
        if (cell < ncells) {
            const float2* cp2 = (const float2*)(pred + (size_t)cell * D_DIM);
            const float2* ct2 = (const float2*)(targ + (size_t)cell * D_DIM);
            float2 pA = cp2[0], pB = cp2[1], pC = cp2[2], pD = cp2[3], pE = cp2[4];
            float2 tA = ct2[0], tB = ct2[1], tC = ct2[2];

            float b1x = pA.x, b1y = pA.y, b1w = pB.x, b1h = pB.y, b1c = pC.x;
            float b2x = pC.y, b2y = pD.x, b2w = pD.y, b2h = pE.x, b2c = pE.y;
            float tbx = tA.x, tby = tA.y, tbw = tB.x, tbh = tB.y;
            float tobj = tC.x;

            const int gxy = cell % (GRID_S * GRID_S);
            const float gy = (float)(gxy / GRID_S);
            const float gx = (float)(gxy % GRID_S);
            const float invS = 1.0f / (float)GRID_S;
            float c1x = (gx + b1x) * invS, c1y = (gy + b1y) * invS;
            float c2x = (gx + b2x) * invS, c2y = (gy + b2y) * invS;
            float ctx = (gx + tbx) * invS, cty = (gy + tby) * invS;

            float iou1 = iou_img(c1x, c1y, b1w, b1h, ctx, cty, tbw, tbh);
            float iou2 = iou_img(c2x, c2y, b2w, b2h, ctx, cty, tbw, tbh);
            bool resp1 = iou1 > iou2;

            float bx = resp1 ? b1x : b2x;
            float by = resp1 ? b1y : b2y;
            float bw = resp1 ? b1w : b2w;
            float bh = resp1 ? b1h : b2h;
            float bc = resp1 ? b1c : b2c;

            bool obj = (tobj == 1.0f);
            float objf = obj ? 1.0f : 0.0f;

            float ddx = bx - tbx, ddy = by - tby;
            float dxy2 = ddx * ddx + ddy * ddy;
            float swpw = sqrtf(fmaxf(bw, EPS_SQRT));
            float swph = sqrtf(fmaxf(bh, EPS_SQRT));
            float swtw = sqrtf(fmaxf(tbw, EPS_SQRT));
            float swth = sqrtf(fmaxf(tbh, EPS_SQRT));
            float dw = swpw - swtw, dh = swph - swth;
            float dwh2 = dw * dw + dh * dh;
            float coord = 0.5f * dxy2 + 0.5f * dwh2;

            float dco = bc - 1.0f;
            float conf_obj = dco * dco;
            float conf_noobj = LAMBDA_NOOBJ * (b1c * b1c + b2c * b2c);

            v_obj = objf;
            v_coord = coord * objf;
            v_conf = obj ? conf_obj : conf_noobj;
        }
    }

    // ---- block reduction (both paths) ----
    #pragma unroll
    for (int off = 32; off > 0; off >>= 1) {
        v_obj   += __shfl_down(v_obj, off, 64);
        v_coord += __shfl_down(v_coord, off, 64);
        v_conf  += __shfl_down(v_conf, off, 64);
        v_cls   += __shfl_down(v_cls, off, 64);
    }
    __shared__ float red[4][4];
    const int lane = tid & 63;
    const int wid = tid >> 6;
    if (lane == 0) {
        red[wid][0] = v_obj;
        red[wid][1] = v_coord;
        red[wid][2] = v_conf;
        red[wid][3] = v_cls;
    }
    __syncthreads();
    if (tid < 4) {
        float s = red[0][tid] + red[1][tid] + red[2][tid] + red[3][tid];
        part[(size_t)blockIdx.x * 4 + tid] = s;
    }
}

__global__ __launch_bounds__(1024) void yolo_final_kernel(
        const float* __restrict__ part, float* __restrict__ out,
        int nblocks, int ncells) {
    const int tid = threadIdx.x;
    float a0 = 0.0f, a1 = 0.0f, a2 = 0.0f, a3 = 0.0f;
    const float4* p4 = (const float4*)part;
    for (int b = tid; b < nblocks; b += 1024) {
        float4 v = p4[b];
        a0 += v.x; a1 += v.y; a2 += v.z; a3 += v.w;
    }
    #pragma unroll
    for (int off = 32; off > 0; off >>= 1) {
        a0 += __shfl_down(a0, off, 64);
        a1 += __shfl_down(a1, off, 64);
        a2 += __shfl_down(a2, off, 64);
        a3 += __shfl_down(a3, off, 64);
    }
    __shared__ float red[16][4];
    const int wid = tid >> 6;
    if ((tid & 63) == 0) {
        red[wid][0] = a0; red[wid][1] = a1; red[wid][2] = a2; red[wid][3] = a3;
    }
    __syncthreads();
    if (tid == 0) {
        float n_obj = 0.0f, coord = 0.0f, conf = 0.0f, cls = 0.0f;
        #pragma unroll
        for (int w = 0; w < 16; ++w) {
            n_obj += red[w][0]; coord += red[w][1];
            conf  += red[w][2]; cls   += red[w][3];
        }
        float n_cells = (float)ncells;
        float conf_count = n_obj + 2.0f * (n_cells - n_obj);
        float denom = fmaxf(n_obj, 1.0f);
        out[0] = LAMBDA_COORD * coord / denom + conf / fmaxf(conf_count, 1.0f) + cls / denom;
    }
}

extern "C" void kernel_launch(void* const* d_in, const int* in_sizes, int n_in,
                              void* d_out, int out_size, void* d_ws, size_t ws_size,
                              hipStream_t stream) {
    const float* pred = (const float*)d_in[0];
    const float* targ = (const float*)d_in[1];
    float* part = (float*)d_ws;
    float* out = (float*)d_out;

    const int ncells = in_sizes[0] / D_DIM;          // B * S * S (even)
    const int GB = (ncells + 255) / 256;             // gather blocks
    const int nblocks = GA + GB;

    yolo_main_kernel<<<nblocks, 256, 0, stream>>>(pred, targ, part, ncells);
    yolo_final_kernel<<<1, 1024, 0, stream>>>(part, out, nblocks, ncells);
}